// Round 1
// baseline (5580.887 us; speedup 1.0000x reference)
//
#include <hip/hip_runtime.h>
#include <math.h>

#define CIN   192
#define C3    576
#define HWSZ  65536   // 256*256

// ---------------------------------------------------------------------------
// K1: fp32 tiled GEMM for qkv 1x1 conv (spatial output, one 192-ch group).
// Mout is derived from gridDim.y (grid.y=3 -> 192 output channels).
// ---------------------------------------------------------------------------
__global__ __launch_bounds__(256) void conv1x1_gemm(
    const float* __restrict__ X, const float* __restrict__ Wm,
    float* __restrict__ Y) {
  __shared__ float As[16][68];
  __shared__ float Bs[16][68];
  const int pt = blockIdx.x * 64;
  const int ot = blockIdx.y * 64;
  const int b  = blockIdx.z;
  const int Mout = gridDim.y * 64;
  const float* Xb = X + (size_t)b * CIN * HWSZ;
  float* Yb = Y + (size_t)b * (size_t)Mout * HWSZ;
  const int tid = threadIdx.x;
  const int tx = tid & 15, ty = tid >> 4;
  const int oA = tid >> 2;
  const int kA = (tid & 3) * 4;
  const int kB = tid >> 4;
  const int pB = (tid & 15) * 4;
  float acc[4][4];
#pragma unroll
  for (int i = 0; i < 4; ++i)
#pragma unroll
    for (int j = 0; j < 4; ++j) acc[i][j] = 0.f;

  for (int k0 = 0; k0 < CIN; k0 += 16) {
    float4 av = *(const float4*)(Wm + (size_t)(ot + oA) * CIN + k0 + kA);
    As[kA + 0][oA] = av.x;
    As[kA + 1][oA] = av.y;
    As[kA + 2][oA] = av.z;
    As[kA + 3][oA] = av.w;
    *(float4*)&Bs[kB][pB] =
        *(const float4*)(Xb + (size_t)(k0 + kB) * HWSZ + pt + pB);
    __syncthreads();
#pragma unroll
    for (int k = 0; k < 16; ++k) {
      const float4 a4 = *(const float4*)&As[k][ty * 4];
      const float4 b4 = *(const float4*)&Bs[k][tx * 4];
      const float avr[4] = {a4.x, a4.y, a4.z, a4.w};
      const float bvr[4] = {b4.x, b4.y, b4.z, b4.w};
#pragma unroll
      for (int i = 0; i < 4; ++i)
#pragma unroll
        for (int j = 0; j < 4; ++j) acc[i][j] += avr[i] * bvr[j];
    }
    __syncthreads();
  }
#pragma unroll
  for (int i = 0; i < 4; ++i) {
    const int o = ot + ty * 4 + i;
    float4 r;
    r.x = acc[i][0]; r.y = acc[i][1]; r.z = acc[i][2]; r.w = acc[i][3];
    *(float4*)(Yb + (size_t)o * HWSZ + pt + tx * 4) = r;
  }
}

// ---------------------------------------------------------------------------
// K2a: depthwise 3x3 conv for one 192-channel group (slice layout
// [b][192][HWSZ]). One block per (slice-channel gc, window-row h1, batch).
// Reads full 256-col contiguous rows, writes windowed layout:
// Bw[((b*1024+win)*576 + gbase+gc)*64 + t].
// LDS tile stride 264, payload at col-offset 4 so float4 stores are
// 16B-aligned (spatial col c <-> index c+4; zero pads at 3 and 260).
// ---------------------------------------------------------------------------
__global__ __launch_bounds__(256) void dwconv_win(
    const float* __restrict__ qkv, const float* __restrict__ wdw,
    float* __restrict__ Bw, int gbase) {
  __shared__ float t[10][264];
  const int gc = blockIdx.x;     // 0..191 within slice
  const int h1 = blockIdx.y;     // 0..31
  const int b  = blockIdx.z;
  const int tid = threadIdx.x;
  const int r0 = h1 * 8 - 1;
  const float* src = qkv + ((size_t)b * 192 + gc) * HWSZ;

  for (int idx = tid; idx < 640; idx += 256) {
    const int row = idx >> 6, cv = idx & 63;
    const int gr = r0 + row;
    float4 v = make_float4(0.f, 0.f, 0.f, 0.f);
    if ((unsigned)gr < 256u) v = *(const float4*)(src + gr * 256 + cv * 4);
    *(float4*)&t[row][4 + cv * 4] = v;
  }
  if (tid < 10) { t[tid][3] = 0.f; t[tid][260] = 0.f; }
  __syncthreads();

  const float* w9 = wdw + (size_t)(gbase + gc) * 9;
  const float w0 = w9[0], w1 = w9[1], w2 = w9[2];
  const float w3 = w9[3], w4 = w9[4], w5 = w9[5];
  const float w6 = w9[6], w7 = w9[7], w8 = w9[8];

  const int c = tid;                  // spatial col 0..255
  const int wv = c >> 3, tt = c & 7;  // window-in-row, token-col
  float* rec = Bw + (((size_t)(b * 1024 + h1 * 32 + wv) * C3) + gbase + gc) * 64
               + tt;

  float x0 = t[0][c + 3], x1 = t[0][c + 4], x2 = t[0][c + 5];
  float y0 = t[1][c + 3], y1 = t[1][c + 4], y2 = t[1][c + 5];
#pragma unroll
  for (int rr = 1; rr <= 8; ++rr) {
    const float z0 = t[rr + 1][c + 3], z1 = t[rr + 1][c + 4],
                z2 = t[rr + 1][c + 5];
    const float res = x0 * w0 + x1 * w1 + x2 * w2
                    + y0 * w3 + y1 * w4 + y2 * w5
                    + z0 * w6 + z1 * w7 + z2 * w8;
    rec[(rr - 1) * 8] = res;
    x0 = y0; x1 = y1; x2 = y2;
    y0 = z0; y1 = z1; y2 = z2;
  }
}

// ---------------------------------------------------------------------------
// K2b: windowed channel attention + mlp gate from windowed dw-qkv.
// One block per (win, head, b). Fully-contiguous float4 global reads.
// LDS stride 68 (16B-aligned rows, conflict-free/2-way patterns).
// ---------------------------------------------------------------------------
__global__ __launch_bounds__(256, 3) void attn_win(
    const float* __restrict__ Bw, const float* __restrict__ temp,
    const float* __restrict__ mlpw, const float* __restrict__ mlpb,
    float* __restrict__ yw) {
  __shared__ float dwv[96 * 68];   // [gc][t]: q 0..31, k 32..63, v 64..95
  __shared__ float mwT[64 * 68];   // [x][y] transposed mlp weights
  __shared__ float attnS[32 * 33];
  __shared__ float scl[64];
  const int head = blockIdx.x % 6;
  const int win  = blockIdx.x / 6;
  const int b    = blockIdx.y;
  const int tid = threadIdx.x;
  const int c8 = tid >> 3, t8 = (tid & 7) * 8;

  const float* rec = Bw + (size_t)(b * 1024 + win) * C3 * 64;
#pragma unroll
  for (int g = 0; g < 3; ++g) {
    const float* s = rec + (g * 192 + head * 32) * 64;
    const float4 v0 = *(const float4*)(s + tid * 8);
    const float4 v1 = *(const float4*)(s + tid * 8 + 4);
    float* d = &dwv[(g * 32 + c8) * 68 + t8];
    *(float4*)d = v0;
    *(float4*)(d + 4) = v1;
  }
  for (int e = tid; e < 4096; e += 256)
    mwT[(e & 63) * 68 + (e >> 6)] = mlpw[e];
  __syncthreads();

  if (tid < 64) {
    float ss = 0.f;
    const float* r = &dwv[tid * 68];
    for (int tt = 0; tt < 64; tt += 4) {
      const float4 v = *(const float4*)(r + tt);
      ss += v.x * v.x + v.y * v.y + v.z * v.z + v.w * v.w;
    }
    scl[tid] = 1.f / fmaxf(sqrtf(ss), 1e-12f);
  }
  __syncthreads();

  // logits + softmax
  {
    const int c = tid >> 3, m = tid & 7;
    float sa[4] = {0.f, 0.f, 0.f, 0.f};
    const float* qr = &dwv[c * 68];
    const float* k0 = &dwv[(32 + m * 4) * 68];
    for (int tt = 0; tt < 64; tt += 4) {
      const float4 q = *(const float4*)(qr + tt);
      const float4 ka = *(const float4*)(k0 + tt);
      const float4 kb = *(const float4*)(k0 + 68 + tt);
      const float4 kc = *(const float4*)(k0 + 136 + tt);
      const float4 kd = *(const float4*)(k0 + 204 + tt);
      sa[0] += q.x * ka.x + q.y * ka.y + q.z * ka.z + q.w * ka.w;
      sa[1] += q.x * kb.x + q.y * kb.y + q.z * kb.z + q.w * kb.w;
      sa[2] += q.x * kc.x + q.y * kc.y + q.z * kc.z + q.w * kc.w;
      sa[3] += q.x * kd.x + q.y * kd.y + q.z * kd.z + q.w * kd.w;
    }
    const float qs = scl[c] * temp[head];
#pragma unroll
    for (int j = 0; j < 4; ++j) sa[j] *= qs * scl[32 + m * 4 + j];
    float mx = fmaxf(fmaxf(sa[0], sa[1]), fmaxf(sa[2], sa[3]));
    for (int off = 1; off < 8; off <<= 1) mx = fmaxf(mx, __shfl_xor(mx, off, 8));
    float sum = 0.f;
#pragma unroll
    for (int j = 0; j < 4; ++j) {
      sa[j] = expf(sa[j] - mx);
      sum += sa[j];
    }
    for (int off = 1; off < 8; off <<= 1) sum += __shfl_xor(sum, off, 8);
    const float inv = 1.f / sum;
#pragma unroll
    for (int j = 0; j < 4; ++j) attnS[c * 33 + m * 4 + j] = sa[j] * inv;
  }
  __syncthreads();

  // out = attn@v ; gate = GELU(v@mlp^T + b) ; y = out*gate
  {
    const int c = tid >> 3, iy = tid & 7;
    float ov[8] = {0.f, 0.f, 0.f, 0.f, 0.f, 0.f, 0.f, 0.f};
    const float* vb = &dwv[64 * 68 + iy * 8];
    const float* as = &attnS[c * 33];
    for (int d = 0; d < 32; ++d) {
      const float a = as[d];
      const float4 x0 = *(const float4*)(vb + d * 68);
      const float4 x1 = *(const float4*)(vb + d * 68 + 4);
      ov[0] += a * x0.x; ov[1] += a * x0.y; ov[2] += a * x0.z; ov[3] += a * x0.w;
      ov[4] += a * x1.x; ov[5] += a * x1.y; ov[6] += a * x1.z; ov[7] += a * x1.w;
    }
    float gt[8];
#pragma unroll
    for (int j = 0; j < 8; ++j) gt[j] = mlpb[iy * 8 + j];
    const float* vc = &dwv[(64 + c) * 68];
    for (int x = 0; x < 64; ++x) {
      const float vv = vc[x];
      const float* mr = &mwT[x * 68 + iy * 8];
      const float4 m0 = *(const float4*)mr;
      const float4 m1 = *(const float4*)(mr + 4);
      gt[0] += vv * m0.x; gt[1] += vv * m0.y; gt[2] += vv * m0.z; gt[3] += vv * m0.w;
      gt[4] += vv * m1.x; gt[5] += vv * m1.y; gt[6] += vv * m1.z; gt[7] += vv * m1.w;
    }
    float res[8];
#pragma unroll
    for (int j = 0; j < 8; ++j) {
      const float gg = gt[j];
      res[j] = ov[j] * (0.5f * gg * (1.f + erff(gg * 0.70710678118654752f)));
    }
    float* dst = yw + (((size_t)(b * 1024 + win) * 192 + head * 32 + c) * 64
                       + iy * 8);
    *(float4*)dst       = make_float4(res[0], res[1], res[2], res[3]);
    *(float4*)(dst + 4) = make_float4(res[4], res[5], res[6], res[7]);
  }
}

// ---------------------------------------------------------------------------
// K3: proj GEMM reading windowed yw, writing spatial out (+bias).
// ---------------------------------------------------------------------------
__global__ __launch_bounds__(256) void proj_gemm(
    const float* __restrict__ yw, const float* __restrict__ Wm,
    const float* __restrict__ bias, float* __restrict__ out) {
  __shared__ float As[16][68];
  __shared__ float Bs[16][256];
  const int ptile = blockIdx.x;
  const int ot = blockIdx.y * 64;
  const int b  = blockIdx.z;
  const int h1 = ptile >> 3, w4 = ptile & 7;
  const int win0 = h1 * 32 + w4 * 4;
  const int tid = threadIdx.x;
  const int tx = tid & 15, ty = tid >> 4;
  const int oA = tid >> 2, kA = (tid & 3) * 4;
  float acc[4][16];
#pragma unroll
  for (int i = 0; i < 4; ++i)
#pragma unroll
    for (int j = 0; j < 16; ++j) acc[i][j] = 0.f;

  const float* ywb = yw + (size_t)(b * 1024 + win0) * 192 * 64;
  for (int k0 = 0; k0 < 192; k0 += 16) {
    float4 av = *(const float4*)(Wm + (size_t)(ot + oA) * 192 + k0 + kA);
    As[kA + 0][oA] = av.x;
    As[kA + 1][oA] = av.y;
    As[kA + 2][oA] = av.z;
    As[kA + 3][oA] = av.w;
#pragma unroll
    for (int i = 0; i < 4; ++i) {
      const int f4 = tid + 256 * i;
      const int k = f4 >> 6, p4 = f4 & 63;
      const int wv = p4 >> 4, tt = (p4 & 15) * 4;
      *(float4*)&Bs[k][p4 * 4] =
          *(const float4*)(ywb + ((size_t)wv * 192 + k0 + k) * 64 + tt);
    }
    __syncthreads();
#pragma unroll
    for (int k = 0; k < 16; ++k) {
      const float a0 = As[k][ty * 4 + 0];
      const float a1 = As[k][ty * 4 + 1];
      const float a2 = As[k][ty * 4 + 2];
      const float a3 = As[k][ty * 4 + 3];
#pragma unroll
      for (int j = 0; j < 16; ++j) {
        const float bv = Bs[k][tx + 16 * j];
        acc[0][j] += a0 * bv;
        acc[1][j] += a1 * bv;
        acc[2][j] += a2 * bv;
        acc[3][j] += a3 * bv;
      }
    }
    __syncthreads();
  }
  const int colbase = w4 * 32;
#pragma unroll
  for (int i = 0; i < 4; ++i) {
    const int o = ot + ty * 4 + i;
    const float bv = bias[o];
    float* ob = out + ((size_t)(b * 192 + o) * 256 + h1 * 8) * 256 + colbase;
#pragma unroll
    for (int j = 0; j < 16; ++j) {
      const int p = tx + 16 * j;
      const int wv = p >> 6;
      const int t = p & 63;
      ob[(t >> 3) * 256 + wv * 8 + (t & 7)] = acc[i][j] + bv;
    }
  }
}

extern "C" void kernel_launch(void* const* d_in, const int* in_sizes, int n_in,
                              void* d_out, int out_size, void* d_ws, size_t ws_size,
                              hipStream_t stream) {
  const float* x           = (const float*)d_in[0];
  const float* w_qkv       = (const float*)d_in[1];
  const float* w_dw        = (const float*)d_in[2];
  const float* temperature = (const float*)d_in[3];
  const float* mlp_w       = (const float*)d_in[4];
  const float* mlp_b       = (const float*)d_in[5];
  const float* proj_w      = (const float*)d_in[6];
  const float* proj_b      = (const float*)d_in[7];
  float* out = (float*)d_out;

  // Workspace layout (402.65 MB total, same footprint as the verified
  // fallback path):
  //   [0 .. 25165824)              slice: spatial conv1x1 output for one
  //                                192-ch group; reused as yw afterwards.
  //   [25165824 .. 100663296)      Bw: windowed dw-qkv, all 576 channels.
  float* slice = (float*)d_ws;
  float* Bw    = slice + (size_t)2 * 192 * HWSZ;   // +25165824

  for (int g = 0; g < 3; ++g) {
    conv1x1_gemm<<<dim3(1024, 3, 2), 256, 0, stream>>>(
        x, w_qkv + (size_t)g * 192 * CIN, slice);
    dwconv_win<<<dim3(192, 32, 2), 256, 0, stream>>>(
        slice, w_dw, Bw, g * 192);
  }
  attn_win<<<dim3(6144, 2), 256, 0, stream>>>(Bw, temperature, mlp_w, mlp_b,
                                              slice);
  proj_gemm<<<dim3(256, 3, 2), 256, 0, stream>>>(slice, proj_w, proj_b, out);
}